// Round 7
// baseline (227.641 us; speedup 1.0000x reference)
//
#include <hip/hip_runtime.h>

// GaussianPooling: fm[512,256,256] f32, keypoints[4096,2] int, out[4096,512] f32.
// 5x5 gaussian sigma=2, separable: k = g(dy)*g(dx)/s^2.
//
// R7: R4-R6 pool ran at only ~2.1 TB/s: 4096 short-lived blocks with
// stage->barrier->compute->exit cohorts leave memory idle half the time
// (same signature as R2's 2.4 TB/s transpose; fills hit 6.8 TB/s).
// Now: 512 persistent channel-blocks (exactly 2/CU), each streams its
// 256-row plane through a 64-row x 256-float LDS ring (64 KB exactly) in
// 16-row strips, software-pipelined: load strip s+2 to VGPRs, compute
// strip s from ring (halo rows of s-1/s+1 are resident), sync, ds_write
// s+2 over retired s-2, sync. fm fetched exactly once (131 MB), prefetch
// latency hidden behind compute. Keypoints bucketed into 16 y-strips.

#define NC  512
#define NH  256
#define NW  256
#define NKP 4096

#define NSTRIP 16            // y-strips of 16 rows
#define RING_ROWS 64         // 4-strip LDS ring, 64*256*4 = 65536 B

// ws layout (int32 offsets):
//   [0..16)                    cnt[16]  (zeroed by hipMemsetAsync)
//   [8192 .. 8192+16*NKP)      packed lists (i | x<<12 | y<<20), stride NKP
#define WS_LIST_OFF_I 8192

// ---------------- bucket: 1 kp/thread, LDS hist + global range reservation ----------------
__global__ __launch_bounds__(256) void bucket_kernel(
    const int* __restrict__ kp, unsigned* __restrict__ ws_i, int n_kp)
{
    __shared__ int hist[NSTRIP];
    __shared__ int base[NSTRIP];
    const int t = threadIdx.x;
    const int i = blockIdx.x * 256 + t;

    if (t < NSTRIP) hist[t] = 0;
    __syncthreads();

    int q = 0, lr = 0;
    unsigned pk = 0;
    const bool valid = (i < n_kp);
    if (valid) {
        int x = kp[2 * i + 0];
        int y = kp[2 * i + 1];
        x = min(max(x, 2), NW - 3);
        y = min(max(y, 2), NH - 3);
        q  = y >> 4;
        lr = atomicAdd(&hist[q], 1);
        pk = (unsigned)i | ((unsigned)x << 12) | ((unsigned)y << 20);
    }
    __syncthreads();

    if (t < NSTRIP) base[t] = atomicAdd((int*)&ws_i[t], hist[t]);
    __syncthreads();

    if (valid)
        ws_i[WS_LIST_OFF_I + q * NKP + base[q] + lr] = pk;
}

// ---------------- pool: block = channel, pipelined 16-row strips through LDS ring ----------------
__global__ __launch_bounds__(256) void pool_kernel(
    const float* __restrict__ fm, const unsigned* __restrict__ ws_i,
    float* __restrict__ out)
{
    __shared__ float ring[RING_ROWS * NW];   // 65,536 B exactly -> 2 blocks/CU

    const int c = blockIdx.x;
    const int t = threadIdx.x;
    const float* plane = fm + ((size_t)c << 16);

    // gaussian weights
    const float e1 = 0.8824969025845955f;  // exp(-1/8)
    const float e2 = 0.6065306597126334f;  // exp(-4/8)
    const float s2 = 2.0f * (e1 + e2) + 1.0f;
    const float inv_s2 = 1.0f / (s2 * s2);
    const float g[5] = {e2, e1, 1.0f, e1, e2};
    float gy[5];
#pragma unroll
    for (int i = 0; i < 5; i++) gy[i] = g[i] * inv_s2;

    float4 pf[4];   // prefetch: strip = 16 rows * 256 f = 1024 float4; 4 per thread

    for (int s = -2; s < NSTRIP; ++s) {
        const int sp = s + 2;

        // 1) issue prefetch of strip sp into VGPRs (consumed only after compute)
        if (sp < NSTRIP) {
            const float4* src = (const float4*)(plane + (sp << 12));
#pragma unroll
            for (int j = 0; j < 4; ++j)
                pf[j] = src[t + j * 256];
        }

        // 2) compute strip s from the ring (strips s-1..s+1 resident)
        if (s >= 0) {
            const int cnt = (int)ws_i[s];
            const unsigned* list = ws_i + WS_LIST_OFF_I + s * NKP;
            for (int e = t; e < cnt; e += 256) {
                const unsigned pk = list[e];
                const int n  = (int)(pk & 0xFFFu);
                const int xc = (int)((pk >> 12) & 0xFFu);
                const int yc = (int)((pk >> 20) & 0xFFu);

                const int x0 = xc - 2;
                const int r  = x0 & 3;
                const int xa = x0 - r;
                float wx[8];
#pragma unroll
                for (int i = 0; i < 8; i++)
                    wx[i] = (i >= r && i < r + 5) ? g[i - r] : 0.0f;

                float acc = 0.0f;
#pragma unroll
                for (int dy = 0; dy < 5; dy++) {
                    const int gr = yc - 2 + dy;               // in [16s-2, 16s+17]
                    const float* rowp = &ring[((gr & (RING_ROWS - 1)) << 8) + xa];
                    float4 a = *(const float4*)rowp;
                    float4 b = *(const float4*)(rowp + 4);
                    acc += gy[dy] * (a.x * wx[0] + a.y * wx[1] + a.z * wx[2] + a.w * wx[3]
                                   + b.x * wx[4] + b.y * wx[5] + b.z * wx[6] + b.w * wx[7]);
                }
                out[(size_t)n * NC + c] = acc;
            }
        }

        __syncthreads();   // all waves done reading strip s-1 (slots of sp&3... safe: sp ≡ s-2 mod 4)

        // 3) commit prefetched strip sp into ring slots (overwrites retired strip s-2)
        if (sp < NSTRIP) {
            float* dst = &ring[(sp & 3) << 12];   // 4096 floats per strip
#pragma unroll
            for (int j = 0; j < 4; ++j)
                *(float4*)&dst[(t + j * 256) << 2] = pf[j];
        }

        __syncthreads();
    }
}

// ---------------- fallback (round-1 direct kernel) ----------------
__global__ __launch_bounds__(256) void gpool_direct_kernel(
    const float* __restrict__ fm, const int* __restrict__ kp,
    float* __restrict__ out)
{
    const int n = blockIdx.x;
    const int t = threadIdx.x;

    int x = kp[2 * n + 0];
    int y = kp[2 * n + 1];
    x = min(max(x, 2), NW - 3);
    y = min(max(y, 2), NH - 3);

    const float e1 = 0.8824969025845955f;
    const float e2 = 0.6065306597126334f;
    const float s  = 2.0f * (e1 + e2) + 1.0f;
    const float inv_s2 = 1.0f / (s * s);
    float g[5] = {e2, e1, 1.0f, e1, e2};
    float gy[5];
#pragma unroll
    for (int i = 0; i < 5; i++) gy[i] = g[i] * inv_s2;

    const int x0 = x - 2;
    const int r  = x0 & 3;
    const int xa = x0 - r;
    float wx[8];
#pragma unroll
    for (int i = 0; i < 8; i++)
        wx[i] = (i >= r && i < r + 5) ? g[i - r] : 0.0f;

    const float* base0 = fm + ((size_t)t * NH + (y - 2)) * NW + xa;
    const float* base1 = fm + ((size_t)(t + 256) * NH + (y - 2)) * NW + xa;

    float acc0 = 0.0f, acc1 = 0.0f;
#pragma unroll
    for (int dy = 0; dy < 5; dy++) {
        const float4* p0 = (const float4*)(base0 + dy * NW);
        const float4* p1 = (const float4*)(base1 + dy * NW);
        float4 a0 = p0[0], b0 = p0[1], a1 = p1[0], b1 = p1[1];
        acc0 += gy[dy] * (a0.x * wx[0] + a0.y * wx[1] + a0.z * wx[2] + a0.w * wx[3]
                        + b0.x * wx[4] + b0.y * wx[5] + b0.z * wx[6] + b0.w * wx[7]);
        acc1 += gy[dy] * (a1.x * wx[0] + a1.y * wx[1] + a1.z * wx[2] + a1.w * wx[3]
                        + b1.x * wx[4] + b1.y * wx[5] + b1.z * wx[6] + b1.w * wx[7]);
    }

    out[(size_t)n * NC + t]       = acc0;
    out[(size_t)n * NC + t + 256] = acc1;
}

extern "C" void kernel_launch(void* const* d_in, const int* in_sizes, int n_in,
                              void* d_out, int out_size, void* d_ws, size_t ws_size,
                              hipStream_t stream)
{
    const float* fm  = (const float*)d_in[0];
    const int*   kp  = (const int*)d_in[1];
    float*       out = (float*)d_out;
    const int n_kp   = in_sizes[1] / 2;   // 4096

    const size_t need = (WS_LIST_OFF_I + (size_t)NSTRIP * NKP) * sizeof(unsigned);
    if (ws_size >= need && n_kp == NKP) {
        unsigned* ws_i = (unsigned*)d_ws;

        hipMemsetAsync(d_ws, 0, NSTRIP * sizeof(unsigned), stream);   // zero cnt[16]

        bucket_kernel<<<(NKP + 255) / 256, 256, 0, stream>>>(kp, ws_i, n_kp);

        pool_kernel<<<NC, 256, 0, stream>>>(fm, ws_i, out);
    } else {
        gpool_direct_kernel<<<n_kp, 256, 0, stream>>>(fm, kp, out);
    }
}